// Round 3
// baseline (199.715 us; speedup 1.0000x reference)
//
#include <hip/hip_runtime.h>
#include <hip/hip_bf16.h>
#include <stdint.h>

typedef __attribute__((ext_vector_type(8))) __bf16 bf16x8;
typedef __attribute__((ext_vector_type(4))) __bf16 bf16x4;
typedef __attribute__((ext_vector_type(4))) float f32x4;
typedef __attribute__((ext_vector_type(4), aligned(4))) float f32x4u;
typedef __attribute__((ext_vector_type(2), aligned(4))) float f32x2u;

#define B_   2
#define M_   4096
#define QH_  16
#define D_   192
#define N_   255
#define VD_  128
#define NP_  256   // padded n

// ---- pre-pass 1: kb[b][h][n(256)][d(192)] bf16, row 255 zeroed ----
__global__ __launch_bounds__(256) void prep_k(const float* __restrict__ k,
                                              __bf16* __restrict__ kb) {
    const int t  = blockIdx.x * 256 + threadIdx.x;
    const int e0 = t * 8;
    const int row = e0 / D_;        // (b*QH+h)*256 + n
    const int d0  = e0 % D_;
    const int n   = row & 255;
    const int bh  = row >> 8;
    const int b   = bh >> 4, h = bh & 15;
    bf16x8 out;
    if (n < N_) {
        const float* src = k + ((size_t)((b * N_ + n) * QH_ + h)) * D_ + d0;
        f32x4 s0 = *(const f32x4*)src;
        f32x4 s1 = *(const f32x4*)(src + 4);
        out[0]=(__bf16)s0[0]; out[1]=(__bf16)s0[1]; out[2]=(__bf16)s0[2]; out[3]=(__bf16)s0[3];
        out[4]=(__bf16)s1[0]; out[5]=(__bf16)s1[1]; out[6]=(__bf16)s1[2]; out[7]=(__bf16)s1[3];
    } else {
        #pragma unroll
        for (int e = 0; e < 8; ++e) out[e] = (__bf16)0.f;
    }
    *(bf16x8*)(kb + (size_t)row * D_ + d0) = out;
}

// ---- pre-pass 2: vt[b][h][vd][n(256)] bf16 transposed, col 255 zeroed ----
__global__ __launch_bounds__(256) void prep_v(const float* __restrict__ v,
                                              __bf16* __restrict__ vt) {
    const int n  = threadIdx.x;          // 0..255
    const int r  = blockIdx.x;           // (b*QH+h)*128 + vd
    const int vd = r & 127;
    const int bh = r >> 7;
    const int b  = bh >> 4, h = bh & 15;
    float val = 0.f;
    if (n < N_) val = v[((size_t)((b * N_ + n) * QH_ + h)) * VD_ + vd];
    vt[(size_t)r * NP_ + n] = (__bf16)val;
}

// ---- main kernel (swapped-operand layout: outputs row-contiguous per lane) ----
__global__ __launch_bounds__(256, 4) void cattn_kernel(
    const float* __restrict__ q, const __bf16* __restrict__ kb,
    const __bf16* __restrict__ vt, float* __restrict__ o_out,
    float* __restrict__ p_out)
{
    const float scale = 0.07216878364870322f; // 192^-0.5
    const int bid = blockIdx.x;
    const int ib  = bid & 63;
    const int h   = (bid >> 6) & 15;
    const int b   = bid >> 10;
    const int bh  = b * QH_ + h;
    const int i0  = ib << 6;

    const int tid  = threadIdx.x;
    const int lane = tid & 63;
    const int wid  = tid >> 6;
    const int g    = lane >> 4;   // 0..3
    const int c16  = lane & 15;
    const int iw   = i0 + wid * 16;
    const int i    = iw + c16;          // this lane's q row (one row per lane!)
    const bool dead = (i < 31);         // fully-masked row -> uniform 1/255

    __shared__ __bf16 pbuf[4][16][264];

    // ---- Q fragment (B-operand): b[e] = Q[i][s*32 + g*8 + e]
    bf16x8 bq[6];
    {
        const float* qrow = q + ((size_t)((b * M_ + i) * QH_ + h)) * D_;
        #pragma unroll
        for (int s = 0; s < 6; ++s) {
            f32x4 q0 = __builtin_nontemporal_load((const f32x4*)(qrow + s * 32 + g * 8));
            f32x4 q1 = __builtin_nontemporal_load((const f32x4*)(qrow + s * 32 + g * 8 + 4));
            bf16x8 a;
            a[0]=(__bf16)q0[0]; a[1]=(__bf16)q0[1]; a[2]=(__bf16)q0[2]; a[3]=(__bf16)q0[3];
            a[4]=(__bf16)q1[0]; a[5]=(__bf16)q1[1]; a[6]=(__bf16)q1[2]; a[7]=(__bf16)q1[3];
            bq[s] = a;
        }
    }

    int jt_any = (iw >= 16) ? ((iw - 16) >> 8) : -1;
    if (jt_any > 15) jt_any = 15;

    // ---- S^T = K Q^T : lane (g,c16) holds S[i][n = jt*16 + g*4 + r]
    const __bf16* kbh = kb + (size_t)bh * NP_ * D_ + (size_t)c16 * D_ + g * 8;
    f32x4 sacc[16];
    #pragma unroll
    for (int jt = 0; jt < 16; ++jt) {
        if (jt <= jt_any) {
            f32x4 acc = {0.f, 0.f, 0.f, 0.f};
            const __bf16* krow = kbh + (size_t)jt * 16 * D_;   // A-row = jt*16 + c16
            #pragma unroll
            for (int s = 0; s < 6; ++s) {
                bf16x8 ka = *(const bf16x8*)(krow + s * 32);
                acc = __builtin_amdgcn_mfma_f32_16x16x32_bf16(ka, bq[s], acc, 0, 0, 0);
            }
            #pragma unroll
            for (int r = 0; r < 4; ++r) {
                const int n = jt * 16 + g * 4 + r;
                const bool ok = (i >= 16 * n + 31) && (n < N_);
                acc[r] = ok ? acc[r] * scale : -1e30f;
            }
            sacc[jt] = acc;
        }
    }

    // ---- softmax over this lane's row (reduce regs + lanes g via xor 16/32)
    float m = -1e30f;
    #pragma unroll
    for (int jt = 0; jt < 16; ++jt) {
        if (jt <= jt_any) {
            #pragma unroll
            for (int r = 0; r < 4; ++r) m = fmaxf(m, sacc[jt][r]);
        }
    }
    m = fmaxf(m, __shfl_xor(m, 16));
    m = fmaxf(m, __shfl_xor(m, 32));
    float sum = 0.f;
    #pragma unroll
    for (int jt = 0; jt < 16; ++jt) {
        if (jt <= jt_any) {
            #pragma unroll
            for (int r = 0; r < 4; ++r) {
                float e = __expf(sacc[jt][r] - m);   // masked: exp(-1e30-m) -> 0
                sacc[jt][r] = e;
                sum += e;
            }
        }
    }
    sum += __shfl_xor(sum, 16);
    sum += __shfl_xor(sum, 32);
    const float inv_l = 1.0f / sum;
    const float u255  = 0.00392156862745098f;  // 1/255 for dead rows

    // ---- write p (vectorized dwordx4, NT) + bf16x4 to LDS
    float* prow = p_out + (size_t)(bh * M_ + i) * N_ + g * 4;
    #pragma unroll
    for (int jt = 0; jt < 16; ++jt) {
        f32x4 px;
        if (jt <= jt_any) {
            #pragma unroll
            for (int r = 0; r < 4; ++r)
                px[r] = dead ? u255 : sacc[jt][r] * inv_l;
        } else {
            const float cz = dead ? u255 : 0.f;
            px = (f32x4){cz, cz, cz, cz};
        }
        if (jt == 15 && g == 3) {
            // cols 252..254 only (col 255 doesn't exist; x4 would corrupt next row)
            f32x2u p2; p2[0] = px[0]; p2[1] = px[1];
            *(f32x2u*)(prow + 15 * 16) = p2;
            prow[15 * 16 + 2] = px[2];
        } else {
            __builtin_nontemporal_store(*(f32x4u*)&px, (f32x4u*)(prow + jt * 16));
        }
        bf16x4 pb;
        #pragma unroll
        for (int r = 0; r < 4; ++r) pb[r] = (__bf16)px[r];
        *(bf16x4*)(&pbuf[wid][c16][jt * 16 + g * 4]) = pb;
    }

    __syncthreads();

    // ---- O^T = V^T P^T : lane (g,c16) holds O[i][vd = vdt*16 + g*4 + r]
    f32x4 oacc[8];
    #pragma unroll
    for (int t = 0; t < 8; ++t) oacc[t] = (f32x4){0.f, 0.f, 0.f, 0.f};

    const __bf16* vth = vt + (size_t)bh * VD_ * NP_ + (size_t)c16 * NP_ + g * 8;
    const int c_lim = (jt_any < 0) ? 0 : ((jt_any + 2) >> 1);
    #pragma unroll
    for (int c = 0; c < 8; ++c) {
        if (c < c_lim) {
            bf16x8 pa = *(const bf16x8*)(&pbuf[wid][c16][c * 32 + g * 8]);
            #pragma unroll
            for (int vdt = 0; vdt < 8; ++vdt) {
                bf16x8 vb = *(const bf16x8*)(vth + (size_t)vdt * 16 * NP_ + c * 32);
                oacc[vdt] = __builtin_amdgcn_mfma_f32_16x16x32_bf16(vb, pa, oacc[vdt], 0, 0, 0);
            }
        }
    }

    // ---- write O (dwordx4 per lane, NT; rows < 31 zeroed)
    float* orow = o_out + ((size_t)(b * M_ + i) * QH_ + h) * VD_ + g * 4;
    #pragma unroll
    for (int vdt = 0; vdt < 8; ++vdt) {
        f32x4 ov;
        #pragma unroll
        for (int r = 0; r < 4; ++r) ov[r] = dead ? 0.f : oacc[vdt][r];
        __builtin_nontemporal_store(*(f32x4u*)&ov, (f32x4u*)(orow + vdt * 16));
    }
}

extern "C" void kernel_launch(void* const* d_in, const int* in_sizes, int n_in,
                              void* d_out, int out_size, void* d_ws, size_t ws_size,
                              hipStream_t stream) {
    (void)in_sizes; (void)n_in; (void)ws_size; (void)out_size;
    const float* q = (const float*)d_in[0];
    const float* k = (const float*)d_in[1];
    const float* v = (const float*)d_in[2];
    float* o_out = (float*)d_out;
    float* p_out = o_out + (size_t)B_ * M_ * QH_ * VD_;   // tuple: (o, p) flat

    __bf16* kb = (__bf16*)d_ws;
    __bf16* vt = kb + (size_t)B_ * QH_ * NP_ * D_;

    prep_k<<<dim3((B_ * QH_ * NP_ * D_ / 8 + 255) / 256), dim3(256), 0, stream>>>(k, kb);
    prep_v<<<dim3(B_ * QH_ * VD_), dim3(256), 0, stream>>>(v, vt);

    dim3 grid(B_ * QH_ * (M_ / 64));   // 2048 blocks
    dim3 block(256);                    // 4 waves x 16 rows
    cattn_kernel<<<grid, block, 0, stream>>>(q, kb, vt, o_out, p_out);
}

// Round 4
// 188.272 us; speedup vs baseline: 1.0608x; 1.0608x over previous
//
#include <hip/hip_runtime.h>
#include <hip/hip_bf16.h>
#include <stdint.h>

typedef __attribute__((ext_vector_type(8))) __bf16 bf16x8;
typedef __attribute__((ext_vector_type(4))) __bf16 bf16x4;
typedef __attribute__((ext_vector_type(4))) float f32x4;
typedef __attribute__((ext_vector_type(4), aligned(4))) float f32x4u;
typedef __attribute__((ext_vector_type(2), aligned(4))) float f32x2u;

#define B_   2
#define M_   4096
#define QH_  16
#define D_   192
#define N_   255
#define VD_  128
#define NP_  256   // padded n

// ---- pre-pass 1: kb[b][h][n(256)][d(192)] bf16, row 255 zeroed ----
__global__ __launch_bounds__(256) void prep_k(const float* __restrict__ k,
                                              __bf16* __restrict__ kb) {
    const int t  = blockIdx.x * 256 + threadIdx.x;
    const int e0 = t * 8;
    const int row = e0 / D_;        // (b*QH+h)*256 + n
    const int d0  = e0 % D_;
    const int n   = row & 255;
    const int bh  = row >> 8;
    const int b   = bh >> 4, h = bh & 15;
    bf16x8 out;
    if (n < N_) {
        const float* src = k + ((size_t)((b * N_ + n) * QH_ + h)) * D_ + d0;
        f32x4 s0 = *(const f32x4*)src;
        f32x4 s1 = *(const f32x4*)(src + 4);
        out[0]=(__bf16)s0[0]; out[1]=(__bf16)s0[1]; out[2]=(__bf16)s0[2]; out[3]=(__bf16)s0[3];
        out[4]=(__bf16)s1[0]; out[5]=(__bf16)s1[1]; out[6]=(__bf16)s1[2]; out[7]=(__bf16)s1[3];
    } else {
        #pragma unroll
        for (int e = 0; e < 8; ++e) out[e] = (__bf16)0.f;
    }
    *(bf16x8*)(kb + (size_t)row * D_ + d0) = out;
}

// ---- pre-pass 2: vt[b][h][vd][n(256)] bf16 transposed, col 255 zeroed ----
__global__ __launch_bounds__(256) void prep_v(const float* __restrict__ v,
                                              __bf16* __restrict__ vt) {
    const int n  = threadIdx.x;          // 0..255
    const int r  = blockIdx.x;           // (b*QH+h)*128 + vd
    const int vd = r & 127;
    const int bh = r >> 7;
    const int b  = bh >> 4, h = bh & 15;
    float val = 0.f;
    if (n < N_) val = v[((size_t)((b * N_ + n) * QH_ + h)) * VD_ + vd];
    vt[(size_t)r * NP_ + n] = (__bf16)val;
}

// ---- main kernel (swapped-operand layout; per-wave XOR-swizzled P buffer) ----
__global__ __launch_bounds__(256, 5) void cattn_kernel(
    const float* __restrict__ q, const __bf16* __restrict__ kb,
    const __bf16* __restrict__ vt, float* __restrict__ o_out,
    float* __restrict__ p_out)
{
    const float scale = 0.07216878364870322f; // 192^-0.5
    const int bid = blockIdx.x;
    const int ib  = bid & 63;
    const int h   = (bid >> 6) & 15;
    const int b   = bid >> 10;
    const int bh  = b * QH_ + h;
    const int i0  = ib << 6;

    const int tid  = threadIdx.x;
    const int lane = tid & 63;
    const int wid  = tid >> 6;
    const int g    = lane >> 4;   // 0..3
    const int c16  = lane & 15;
    const int iw   = i0 + wid * 16;
    const int i    = iw + c16;          // this lane's q row
    const bool dead = (i < 31);         // fully-masked row -> uniform 1/255

    // per-wave P staging: [wave][row(16)][256] bf16, XOR-swizzled (no pad) = 32 KiB
    __shared__ __bf16 pbuf[4][16][256];
    char* pb = (char*)pbuf;
    const int swzm  = (c16 & 7) << 4;                      // XOR mask, bits 4-6
    const int wbase = (wid << 13) + (c16 << 9) + (g << 3); // b64 write base
    const int rbase = (wid << 13) + (c16 << 9) + (g << 4); // b128 read base

    // ---- Q fragment (B-operand): b[e] = Q[i][s*32 + g*8 + e]
    bf16x8 bq[6];
    {
        const float* qrow = q + ((size_t)((b * M_ + i) * QH_ + h)) * D_;
        #pragma unroll
        for (int s = 0; s < 6; ++s) {
            f32x4 q0 = __builtin_nontemporal_load((const f32x4*)(qrow + s * 32 + g * 8));
            f32x4 q1 = __builtin_nontemporal_load((const f32x4*)(qrow + s * 32 + g * 8 + 4));
            bf16x8 a;
            a[0]=(__bf16)q0[0]; a[1]=(__bf16)q0[1]; a[2]=(__bf16)q0[2]; a[3]=(__bf16)q0[3];
            a[4]=(__bf16)q1[0]; a[5]=(__bf16)q1[1]; a[6]=(__bf16)q1[2]; a[7]=(__bf16)q1[3];
            bq[s] = a;
        }
    }

    int jt_any = (iw >= 16) ? ((iw - 16) >> 8) : -1;
    if (jt_any > 15) jt_any = 15;

    // ---- S^T = K Q^T : lane (g,c16) holds S[i][n = jt*16 + g*4 + r]
    const __bf16* kbh = kb + (size_t)bh * NP_ * D_ + (size_t)c16 * D_ + g * 8;
    f32x4 sacc[16];
    #pragma unroll
    for (int jt = 0; jt < 16; ++jt) {
        if (jt <= jt_any) {
            f32x4 acc = {0.f, 0.f, 0.f, 0.f};
            const __bf16* krow = kbh + (size_t)jt * 16 * D_;   // A-row = jt*16 + c16
            #pragma unroll
            for (int s = 0; s < 6; ++s) {
                bf16x8 ka = *(const bf16x8*)(krow + s * 32);
                acc = __builtin_amdgcn_mfma_f32_16x16x32_bf16(ka, bq[s], acc, 0, 0, 0);
            }
            #pragma unroll
            for (int r = 0; r < 4; ++r) {
                const int n = jt * 16 + g * 4 + r;
                const bool ok = (i >= 16 * n + 31) && (n < N_);
                acc[r] = ok ? acc[r] * scale : -1e30f;
            }
            sacc[jt] = acc;
        }
    }

    // ---- softmax over this lane's row (reduce regs + xor 16/32)
    float m = -1e30f;
    #pragma unroll
    for (int jt = 0; jt < 16; ++jt) {
        if (jt <= jt_any) {
            #pragma unroll
            for (int r = 0; r < 4; ++r) m = fmaxf(m, sacc[jt][r]);
        }
    }
    m = fmaxf(m, __shfl_xor(m, 16));
    m = fmaxf(m, __shfl_xor(m, 32));
    float sum = 0.f;
    #pragma unroll
    for (int jt = 0; jt < 16; ++jt) {
        if (jt <= jt_any) {
            #pragma unroll
            for (int r = 0; r < 4; ++r) {
                float e = __expf(sacc[jt][r] - m);   // masked: -> 0
                sacc[jt][r] = e;
                sum += e;
            }
        }
    }
    sum += __shfl_xor(sum, 16);
    sum += __shfl_xor(sum, 32);
    const float inv_l = 1.0f / sum;
    const float u255  = 0.00392156862745098f;  // 1/255 for dead rows

    // ---- write p (plain cached stores; L2 write-back combines odd-stride rows)
    float* prow = p_out + (size_t)(bh * M_ + i) * N_ + g * 4;
    #pragma unroll
    for (int jt = 0; jt < 16; ++jt) {
        f32x4 px;
        if (jt <= jt_any) {
            #pragma unroll
            for (int r = 0; r < 4; ++r)
                px[r] = dead ? u255 : sacc[jt][r] * inv_l;
        } else {
            const float cz = dead ? u255 : 0.f;
            px = (f32x4){cz, cz, cz, cz};
        }
        if (jt == 15 && g == 3) {
            // cols 252..254 only (col 255 doesn't exist)
            f32x2u p2; p2[0] = px[0]; p2[1] = px[1];
            *(f32x2u*)(prow + 15 * 16) = p2;
            prow[15 * 16 + 2] = px[2];
        } else {
            *(f32x4u*)(prow + jt * 16) = *(f32x4u*)&px;
        }
        bf16x4 pbv;
        #pragma unroll
        for (int r = 0; r < 4; ++r) pbv[r] = (__bf16)px[r];
        *(bf16x4*)(pb + ((wbase + (jt << 5)) ^ swzm)) = pbv;
    }

    // NOTE: no __syncthreads() — pbuf slice [wid] is produced and consumed by
    // the same wave; same-wave DS ordering + compiler lgkmcnt handles the RAW.

    // ---- O^T = V^T P^T : lane (g,c16) holds O[i][vd = vdt*16 + g*4 + r]
    f32x4 oacc[8];
    #pragma unroll
    for (int t = 0; t < 8; ++t) oacc[t] = (f32x4){0.f, 0.f, 0.f, 0.f};

    const __bf16* vth = vt + (size_t)bh * VD_ * NP_ + (size_t)c16 * NP_ + g * 8;
    const int c_lim = (jt_any < 0) ? 0 : ((jt_any + 2) >> 1);
    #pragma unroll
    for (int c = 0; c < 8; ++c) {
        if (c < c_lim) {
            bf16x8 pa = *(const bf16x8*)(pb + ((rbase + (c << 6)) ^ swzm));
            #pragma unroll
            for (int vdt = 0; vdt < 8; ++vdt) {
                bf16x8 vb = *(const bf16x8*)(vth + (size_t)vdt * 16 * NP_ + c * 32);
                oacc[vdt] = __builtin_amdgcn_mfma_f32_16x16x32_bf16(vb, pa, oacc[vdt], 0, 0, 0);
            }
        }
    }

    // ---- write O (plain dwordx4, 16B-aligned; rows < 31 zeroed)
    float* orow = o_out + ((size_t)(b * M_ + i) * QH_ + h) * VD_ + g * 4;
    #pragma unroll
    for (int vdt = 0; vdt < 8; ++vdt) {
        f32x4 ov;
        #pragma unroll
        for (int r = 0; r < 4; ++r) ov[r] = dead ? 0.f : oacc[vdt][r];
        *(f32x4*)(orow + vdt * 16) = ov;
    }
}

extern "C" void kernel_launch(void* const* d_in, const int* in_sizes, int n_in,
                              void* d_out, int out_size, void* d_ws, size_t ws_size,
                              hipStream_t stream) {
    (void)in_sizes; (void)n_in; (void)ws_size; (void)out_size;
    const float* q = (const float*)d_in[0];
    const float* k = (const float*)d_in[1];
    const float* v = (const float*)d_in[2];
    float* o_out = (float*)d_out;
    float* p_out = o_out + (size_t)B_ * M_ * QH_ * VD_;   // tuple: (o, p) flat

    __bf16* kb = (__bf16*)d_ws;
    __bf16* vt = kb + (size_t)B_ * QH_ * NP_ * D_;

    prep_k<<<dim3((B_ * QH_ * NP_ * D_ / 8 + 255) / 256), dim3(256), 0, stream>>>(k, kb);
    prep_v<<<dim3(B_ * QH_ * VD_), dim3(256), 0, stream>>>(v, vt);

    dim3 grid(B_ * QH_ * (M_ / 64));   // 2048 blocks
    dim3 block(256);                    // 4 waves x 16 rows
    cattn_kernel<<<grid, block, 0, stream>>>(q, kb, vt, o_out, p_out);
}

// Round 5
// 176.844 us; speedup vs baseline: 1.1293x; 1.0646x over previous
//
#include <hip/hip_runtime.h>
#include <hip/hip_bf16.h>
#include <stdint.h>

typedef __attribute__((ext_vector_type(8))) __bf16 bf16x8;
typedef __attribute__((ext_vector_type(4))) __bf16 bf16x4;
typedef __attribute__((ext_vector_type(4))) float f32x4;
typedef __attribute__((ext_vector_type(4), aligned(4))) float f32x4u;
typedef __attribute__((ext_vector_type(2), aligned(4))) float f32x2u;

#define B_   2
#define M_   4096
#define QH_  16
#define D_   192
#define N_   255
#define VD_  128
#define NP_  256   // padded n

// ---- pre-pass 1: kb[b][h][n(256)][d(192)] bf16, row 255 zeroed ----
__global__ __launch_bounds__(256) void prep_k(const float* __restrict__ k,
                                              __bf16* __restrict__ kb) {
    const int t  = blockIdx.x * 256 + threadIdx.x;
    const int e0 = t * 8;
    const int row = e0 / D_;        // (b*QH+h)*256 + n
    const int d0  = e0 % D_;
    const int n   = row & 255;
    const int bh  = row >> 8;
    const int b   = bh >> 4, h = bh & 15;
    bf16x8 out;
    if (n < N_) {
        const float* src = k + ((size_t)((b * N_ + n) * QH_ + h)) * D_ + d0;
        f32x4 s0 = *(const f32x4*)src;
        f32x4 s1 = *(const f32x4*)(src + 4);
        out[0]=(__bf16)s0[0]; out[1]=(__bf16)s0[1]; out[2]=(__bf16)s0[2]; out[3]=(__bf16)s0[3];
        out[4]=(__bf16)s1[0]; out[5]=(__bf16)s1[1]; out[6]=(__bf16)s1[2]; out[7]=(__bf16)s1[3];
    } else {
        #pragma unroll
        for (int e = 0; e < 8; ++e) out[e] = (__bf16)0.f;
    }
    *(bf16x8*)(kb + (size_t)row * D_ + d0) = out;
}

// ---- pre-pass 2: vt[b][h][vd][n(256)] bf16 transposed, col 255 zeroed ----
__global__ __launch_bounds__(256) void prep_v(const float* __restrict__ v,
                                              __bf16* __restrict__ vt) {
    const int n  = threadIdx.x;          // 0..255
    const int r  = blockIdx.x;           // (b*QH+h)*128 + vd
    const int vd = r & 127;
    const int bh = r >> 7;
    const int b  = bh >> 4, h = bh & 15;
    float val = 0.f;
    if (n < N_) val = v[((size_t)((b * N_ + n) * QH_ + h)) * VD_ + vd];
    vt[(size_t)r * NP_ + n] = (__bf16)val;
}

// ---- main kernel: swapped-operand layout, zero LDS, shuffle P-redistribution
__global__ __launch_bounds__(256, 3) void cattn_kernel(
    const float* __restrict__ q, const __bf16* __restrict__ kb,
    const __bf16* __restrict__ vt, float* __restrict__ o_out,
    float* __restrict__ p_out)
{
    const float scale = 0.07216878364870322f; // 192^-0.5
    const int bid = blockIdx.x;
    const int ib  = 63 - (bid & 63);   // LPT: heavy q-blocks dispatched first
    const int h   = (bid >> 6) & 15;
    const int b   = bid >> 10;
    const int bh  = b * QH_ + h;
    const int i0  = ib << 6;

    const int tid  = threadIdx.x;
    const int lane = tid & 63;
    const int wid  = tid >> 6;
    const int g    = lane >> 4;   // 0..3
    const int c16  = lane & 15;
    const int iw   = i0 + wid * 16;
    const int i    = iw + c16;          // this lane's q row
    const bool dead = (i < 31);         // fully-masked row -> uniform 1/255

    // ---- Q fragment (B-operand): b[e] = Q[i][s*32 + g*8 + e]
    bf16x8 bq[6];
    {
        const float* qrow = q + ((size_t)((b * M_ + i) * QH_ + h)) * D_;
        #pragma unroll
        for (int s = 0; s < 6; ++s) {
            f32x4 q0 = __builtin_nontemporal_load((const f32x4*)(qrow + s * 32 + g * 8));
            f32x4 q1 = __builtin_nontemporal_load((const f32x4*)(qrow + s * 32 + g * 8 + 4));
            bf16x8 a;
            a[0]=(__bf16)q0[0]; a[1]=(__bf16)q0[1]; a[2]=(__bf16)q0[2]; a[3]=(__bf16)q0[3];
            a[4]=(__bf16)q1[0]; a[5]=(__bf16)q1[1]; a[6]=(__bf16)q1[2]; a[7]=(__bf16)q1[3];
            bq[s] = a;
        }
    }

    int jt_any = (iw >= 16) ? ((iw - 16) >> 8) : -1;
    if (jt_any > 15) jt_any = 15;

    // ---- S^T = K Q^T : lane (g,c16) holds S[i][n = jt*16 + g*4 + r]
    const __bf16* kbh = kb + (size_t)bh * NP_ * D_ + (size_t)c16 * D_ + g * 8;
    f32x4 sacc[16];
    #pragma unroll
    for (int jt = 0; jt < 16; ++jt) {
        if (jt <= jt_any) {
            f32x4 acc = {0.f, 0.f, 0.f, 0.f};
            const __bf16* krow = kbh + (size_t)jt * 16 * D_;   // A-row = jt*16 + c16
            #pragma unroll
            for (int s = 0; s < 6; ++s) {
                bf16x8 ka = *(const bf16x8*)(krow + s * 32);
                acc = __builtin_amdgcn_mfma_f32_16x16x32_bf16(ka, bq[s], acc, 0, 0, 0);
            }
            #pragma unroll
            for (int r = 0; r < 4; ++r) {
                const int n = jt * 16 + g * 4 + r;
                const bool ok = (i >= 16 * n + 31) && (n < N_);
                acc[r] = ok ? acc[r] * scale : -1e30f;
            }
            sacc[jt] = acc;
        }
    }

    // ---- softmax over this lane's row (reduce regs + xor 16/32)
    float m = -1e30f;
    #pragma unroll
    for (int jt = 0; jt < 16; ++jt) {
        if (jt <= jt_any) {
            #pragma unroll
            for (int r = 0; r < 4; ++r) m = fmaxf(m, sacc[jt][r]);
        }
    }
    m = fmaxf(m, __shfl_xor(m, 16));
    m = fmaxf(m, __shfl_xor(m, 32));
    float sum = 0.f;
    #pragma unroll
    for (int jt = 0; jt < 16; ++jt) {
        if (jt <= jt_any) {
            #pragma unroll
            for (int r = 0; r < 4; ++r) {
                float e = __expf(sacc[jt][r] - m);   // masked -> exact 0
                sacc[jt][r] = e;
                sum += e;
            }
        }
    }
    sum += __shfl_xor(sum, 16);
    sum += __shfl_xor(sum, 32);
    const float inv_l = 1.0f / sum;
    const float u255  = 0.00392156862745098f;  // 1/255 for dead rows

    // ---- normalize, store p (vector, cached), pack bf16x4 -> u64 for shuffles
    unsigned long long pnp[16];
    float* prow = p_out + (size_t)(bh * M_ + i) * N_ + g * 4;
    #pragma unroll
    for (int jt = 0; jt < 16; ++jt) {
        f32x4 px;
        if (jt <= jt_any) {
            #pragma unroll
            for (int r = 0; r < 4; ++r)
                px[r] = dead ? u255 : sacc[jt][r] * inv_l;
        } else {
            const float cz = dead ? u255 : 0.f;
            px = (f32x4){cz, cz, cz, cz};
        }
        if (jt == 15 && g == 3) {
            // cols 252..254 only (col 255 doesn't exist)
            f32x2u p2; p2[0] = px[0]; p2[1] = px[1];
            *(f32x2u*)(prow + 15 * 16) = p2;
            prow[15 * 16 + 2] = px[2];
        } else {
            *(f32x4u*)(prow + jt * 16) = *(f32x4u*)&px;
        }
        union { bf16x4 v; unsigned long long u; } pk;
        #pragma unroll
        for (int r = 0; r < 4; ++r) pk.v[r] = (__bf16)px[r];
        pnp[jt] = (jt <= jt_any) ? pk.u : 0ULL;   // masked tiles contribute 0 to PV
    }

    // ---- O^T = V^T P^T : lane (g,c16) holds O[i][vd = vdt*16 + g*4 + r]
    // B-frag pa[e] = P[i = iw+c16][n = c*32 + g*8 + e]; source values live in
    // lanes (g_s, c16) with g_s = (g&1)*2 + (e>>2), jt = 2c + (g>>1), r = e&3.
    f32x4 oacc[8];
    #pragma unroll
    for (int t = 0; t < 8; ++t) oacc[t] = (f32x4){0.f, 0.f, 0.f, 0.f};

    const __bf16* vth = vt + (size_t)bh * VD_ * NP_ + (size_t)c16 * NP_ + g * 8;
    const int src0 = ((g & 1) << 5) + c16;   // lane (g_s=(g&1)*2, c16)
    const int src1 = src0 + 16;              // lane (g_s=(g&1)*2+1, c16)
    const bool selhi = (g >= 2);
    const int c_lim = (jt_any < 0) ? 0 : ((jt_any + 2) >> 1);
    #pragma unroll
    for (int c = 0; c < 8; ++c) {
        if (c < c_lim) {
            unsigned long long lo0 = __shfl(pnp[2 * c],     src0);
            unsigned long long lo1 = __shfl(pnp[2 * c + 1], src0);
            unsigned long long hi0 = __shfl(pnp[2 * c],     src1);
            unsigned long long hi1 = __shfl(pnp[2 * c + 1], src1);
            union { struct { unsigned long long x, y; } u; bf16x8 v; } pa8;
            pa8.u.x = selhi ? lo1 : lo0;
            pa8.u.y = selhi ? hi1 : hi0;
            const bf16x8 pa = pa8.v;
            #pragma unroll
            for (int vdt = 0; vdt < 8; ++vdt) {
                bf16x8 vb = *(const bf16x8*)(vth + (size_t)vdt * 16 * NP_ + c * 32);
                oacc[vdt] = __builtin_amdgcn_mfma_f32_16x16x32_bf16(vb, pa, oacc[vdt], 0, 0, 0);
            }
        }
    }

    // ---- write O (dwordx4 per lane; rows < 31 zeroed)
    float* orow = o_out + ((size_t)(b * M_ + i) * QH_ + h) * VD_ + g * 4;
    #pragma unroll
    for (int vdt = 0; vdt < 8; ++vdt) {
        f32x4 ov;
        #pragma unroll
        for (int r = 0; r < 4; ++r) ov[r] = dead ? 0.f : oacc[vdt][r];
        *(f32x4*)(orow + vdt * 16) = ov;
    }
}

extern "C" void kernel_launch(void* const* d_in, const int* in_sizes, int n_in,
                              void* d_out, int out_size, void* d_ws, size_t ws_size,
                              hipStream_t stream) {
    (void)in_sizes; (void)n_in; (void)ws_size; (void)out_size;
    const float* q = (const float*)d_in[0];
    const float* k = (const float*)d_in[1];
    const float* v = (const float*)d_in[2];
    float* o_out = (float*)d_out;
    float* p_out = o_out + (size_t)B_ * M_ * QH_ * VD_;   // tuple: (o, p) flat

    __bf16* kb = (__bf16*)d_ws;
    __bf16* vt = kb + (size_t)B_ * QH_ * NP_ * D_;

    prep_k<<<dim3((B_ * QH_ * NP_ * D_ / 8 + 255) / 256), dim3(256), 0, stream>>>(k, kb);
    prep_v<<<dim3(B_ * QH_ * VD_), dim3(256), 0, stream>>>(v, vt);

    dim3 grid(B_ * QH_ * (M_ / 64));   // 2048 blocks
    dim3 block(256);                    // 4 waves x 16 rows
    cattn_kernel<<<grid, block, 0, stream>>>(q, kb, vt, o_out, p_out);
}

// Round 6
// 149.161 us; speedup vs baseline: 1.3389x; 1.1856x over previous
//
#include <hip/hip_runtime.h>
#include <hip/hip_bf16.h>
#include <stdint.h>

typedef __attribute__((ext_vector_type(8))) __bf16 bf16x8;
typedef __attribute__((ext_vector_type(4))) __bf16 bf16x4;
typedef __attribute__((ext_vector_type(4))) float f32x4;
typedef __attribute__((ext_vector_type(4), aligned(4))) float f32x4u;
typedef __attribute__((ext_vector_type(2), aligned(4))) float f32x2u;

#define B_   2
#define M_   4096
#define QH_  16
#define D_   192
#define N_   255
#define VD_  128
#define NP_  256   // padded n

// ---- pre-pass 1: kb[b][h][n(256)][d(192)] bf16, row 255 zeroed ----
__global__ __launch_bounds__(256) void prep_k(const float* __restrict__ k,
                                              __bf16* __restrict__ kb) {
    const int t  = blockIdx.x * 256 + threadIdx.x;
    const int e0 = t * 8;
    const int row = e0 / D_;        // (b*QH+h)*256 + n
    const int d0  = e0 % D_;
    const int n   = row & 255;
    const int bh  = row >> 8;
    const int b   = bh >> 4, h = bh & 15;
    bf16x8 out;
    if (n < N_) {
        const float* src = k + ((size_t)((b * N_ + n) * QH_ + h)) * D_ + d0;
        f32x4 s0 = *(const f32x4*)src;
        f32x4 s1 = *(const f32x4*)(src + 4);
        out[0]=(__bf16)s0[0]; out[1]=(__bf16)s0[1]; out[2]=(__bf16)s0[2]; out[3]=(__bf16)s0[3];
        out[4]=(__bf16)s1[0]; out[5]=(__bf16)s1[1]; out[6]=(__bf16)s1[2]; out[7]=(__bf16)s1[3];
    } else {
        #pragma unroll
        for (int e = 0; e < 8; ++e) out[e] = (__bf16)0.f;
    }
    *(bf16x8*)(kb + (size_t)row * D_ + d0) = out;
}

// ---- pre-pass 2: vt[b][h][vd][n(256)] bf16 transposed, col 255 zeroed ----
__global__ __launch_bounds__(256) void prep_v(const float* __restrict__ v,
                                              __bf16* __restrict__ vt) {
    const int n  = threadIdx.x;          // 0..255
    const int r  = blockIdx.x;           // (b*QH+h)*128 + vd
    const int vd = r & 127;
    const int bh = r >> 7;
    const int b  = bh >> 4, h = bh & 15;
    float val = 0.f;
    if (n < N_) val = v[((size_t)((b * N_ + n) * QH_ + h)) * VD_ + vd];
    vt[(size_t)r * NP_ + n] = (__bf16)val;
}

// ---- main kernel: ONE WAVE per block (16 q-rows), HW-queue load balancing ----
__global__ __launch_bounds__(64) void cattn_kernel(
    const float* __restrict__ q, const __bf16* __restrict__ kb,
    const __bf16* __restrict__ vt, float* __restrict__ o_out,
    float* __restrict__ p_out)
{
    const float scale = 0.07216878364870322f; // 192^-0.5
    const int bid  = blockIdx.x;
    const int iw16 = 255 - (bid & 255);   // heavy q-tiles dispatched first
    const int h    = (bid >> 8) & 15;
    const int b    = bid >> 12;
    const int bh   = b * QH_ + h;

    const int lane = threadIdx.x;   // 0..63
    const int g    = lane >> 4;     // 0..3
    const int c16  = lane & 15;
    const int iw   = iw16 << 4;
    const int i    = iw + c16;          // this lane's q row
    const bool dead = (i < 31);         // fully-masked row -> uniform 1/255

    // ---- Q fragment (B-operand): b[e] = Q[i][s*32 + g*8 + e]
    bf16x8 bq[6];
    {
        const float* qrow = q + ((size_t)((b * M_ + i) * QH_ + h)) * D_;
        #pragma unroll
        for (int s = 0; s < 6; ++s) {
            f32x4 q0 = __builtin_nontemporal_load((const f32x4*)(qrow + s * 32 + g * 8));
            f32x4 q1 = __builtin_nontemporal_load((const f32x4*)(qrow + s * 32 + g * 8 + 4));
            bf16x8 a;
            a[0]=(__bf16)q0[0]; a[1]=(__bf16)q0[1]; a[2]=(__bf16)q0[2]; a[3]=(__bf16)q0[3];
            a[4]=(__bf16)q1[0]; a[5]=(__bf16)q1[1]; a[6]=(__bf16)q1[2]; a[7]=(__bf16)q1[3];
            bq[s] = a;
        }
    }

    int jt_any = (iw >= 16) ? ((iw - 16) >> 8) : -1;
    if (jt_any > 15) jt_any = 15;

    // ---- S^T = K Q^T : lane (g,c16) holds S[i][n = jt*16 + g*4 + r]
    const __bf16* kbh = kb + (size_t)bh * NP_ * D_ + (size_t)c16 * D_ + g * 8;
    f32x4 sacc[16];
    #pragma unroll
    for (int jt = 0; jt < 16; ++jt) {
        if (jt <= jt_any) {
            f32x4 acc = {0.f, 0.f, 0.f, 0.f};
            const __bf16* krow = kbh + (size_t)jt * 16 * D_;   // A-row = jt*16 + c16
            #pragma unroll
            for (int s = 0; s < 6; ++s) {
                bf16x8 ka = *(const bf16x8*)(krow + s * 32);
                acc = __builtin_amdgcn_mfma_f32_16x16x32_bf16(ka, bq[s], acc, 0, 0, 0);
            }
            #pragma unroll
            for (int r = 0; r < 4; ++r) {
                const int n = jt * 16 + g * 4 + r;
                const bool ok = (i >= 16 * n + 31) && (n < N_);
                acc[r] = ok ? acc[r] * scale : -1e30f;
            }
            sacc[jt] = acc;
        }
    }

    // ---- softmax over this lane's row (reduce regs + xor 16/32)
    float m = -1e30f;
    #pragma unroll
    for (int jt = 0; jt < 16; ++jt) {
        if (jt <= jt_any) {
            #pragma unroll
            for (int r = 0; r < 4; ++r) m = fmaxf(m, sacc[jt][r]);
        }
    }
    m = fmaxf(m, __shfl_xor(m, 16));
    m = fmaxf(m, __shfl_xor(m, 32));
    float sum = 0.f;
    #pragma unroll
    for (int jt = 0; jt < 16; ++jt) {
        if (jt <= jt_any) {
            #pragma unroll
            for (int r = 0; r < 4; ++r) {
                float e = __expf(sacc[jt][r] - m);   // masked -> exact 0
                sacc[jt][r] = e;
                sum += e;
            }
        }
    }
    sum += __shfl_xor(sum, 16);
    sum += __shfl_xor(sum, 32);
    const float inv_l = 1.0f / sum;
    const float u255  = 0.00392156862745098f;  // 1/255 for dead rows

    // ---- normalize, store p (vector, cached), pack bf16x4 -> u64 for shuffles
    unsigned long long pnp[16];
    float* prow = p_out + (size_t)(bh * M_ + i) * N_ + g * 4;
    #pragma unroll
    for (int jt = 0; jt < 16; ++jt) {
        f32x4 px;
        if (jt <= jt_any) {
            #pragma unroll
            for (int r = 0; r < 4; ++r)
                px[r] = dead ? u255 : sacc[jt][r] * inv_l;
        } else {
            const float cz = dead ? u255 : 0.f;
            px = (f32x4){cz, cz, cz, cz};
        }
        if (jt == 15 && g == 3) {
            // cols 252..254 only (col 255 doesn't exist)
            f32x2u p2; p2[0] = px[0]; p2[1] = px[1];
            *(f32x2u*)(prow + 15 * 16) = p2;
            prow[15 * 16 + 2] = px[2];
        } else {
            *(f32x4u*)(prow + jt * 16) = *(f32x4u*)&px;
        }
        union { bf16x4 v; unsigned long long u; } pk;
        #pragma unroll
        for (int r = 0; r < 4; ++r) pk.v[r] = (__bf16)px[r];
        pnp[jt] = (jt <= jt_any) ? pk.u : 0ULL;   // masked tiles contribute 0 to PV
    }

    // ---- O^T = V^T P^T : lane (g,c16) holds O[i][vd = vdt*16 + g*4 + r]
    f32x4 oacc[8];
    #pragma unroll
    for (int t = 0; t < 8; ++t) oacc[t] = (f32x4){0.f, 0.f, 0.f, 0.f};

    const __bf16* vth = vt + (size_t)bh * VD_ * NP_ + (size_t)c16 * NP_ + g * 8;
    const int src0 = ((g & 1) << 5) + c16;   // lane (g_s=(g&1)*2, c16)
    const int src1 = src0 + 16;              // lane (g_s=(g&1)*2+1, c16)
    const bool selhi = (g >= 2);
    const int c_lim = (jt_any < 0) ? 0 : ((jt_any + 2) >> 1);
    #pragma unroll
    for (int c = 0; c < 8; ++c) {
        if (c < c_lim) {
            unsigned long long lo0 = __shfl(pnp[2 * c],     src0);
            unsigned long long lo1 = __shfl(pnp[2 * c + 1], src0);
            unsigned long long hi0 = __shfl(pnp[2 * c],     src1);
            unsigned long long hi1 = __shfl(pnp[2 * c + 1], src1);
            union { struct { unsigned long long x, y; } u; bf16x8 v; } pa8;
            pa8.u.x = selhi ? lo1 : lo0;
            pa8.u.y = selhi ? hi1 : hi0;
            const bf16x8 pa = pa8.v;
            #pragma unroll
            for (int vdt = 0; vdt < 8; ++vdt) {
                bf16x8 vb = *(const bf16x8*)(vth + (size_t)vdt * 16 * NP_ + c * 32);
                oacc[vdt] = __builtin_amdgcn_mfma_f32_16x16x32_bf16(vb, pa, oacc[vdt], 0, 0, 0);
            }
        }
    }

    // ---- write O (dwordx4 per lane; rows < 31 zeroed)
    float* orow = o_out + ((size_t)(b * M_ + i) * QH_ + h) * VD_ + g * 4;
    #pragma unroll
    for (int vdt = 0; vdt < 8; ++vdt) {
        f32x4 ov;
        #pragma unroll
        for (int r = 0; r < 4; ++r) ov[r] = dead ? 0.f : oacc[vdt][r];
        *(f32x4*)(orow + vdt * 16) = ov;
    }
}

extern "C" void kernel_launch(void* const* d_in, const int* in_sizes, int n_in,
                              void* d_out, int out_size, void* d_ws, size_t ws_size,
                              hipStream_t stream) {
    (void)in_sizes; (void)n_in; (void)ws_size; (void)out_size;
    const float* q = (const float*)d_in[0];
    const float* k = (const float*)d_in[1];
    const float* v = (const float*)d_in[2];
    float* o_out = (float*)d_out;
    float* p_out = o_out + (size_t)B_ * M_ * QH_ * VD_;   // tuple: (o, p) flat

    __bf16* kb = (__bf16*)d_ws;
    __bf16* vt = kb + (size_t)B_ * QH_ * NP_ * D_;

    prep_k<<<dim3((B_ * QH_ * NP_ * D_ / 8 + 255) / 256), dim3(256), 0, stream>>>(k, kb);
    prep_v<<<dim3(B_ * QH_ * VD_), dim3(256), 0, stream>>>(v, vt);

    dim3 grid(B_ * QH_ * 256);   // 8192 one-wave blocks: (b, h, 16-row q-tile)
    dim3 block(64);
    cattn_kernel<<<grid, block, 0, stream>>>(q, kb, vt, o_out, p_out);
}